// Round 5
// baseline (212.778 us; speedup 1.0000x reference)
//
#include <hip/hip_runtime.h>

// Separable 3D Gaussian blur (sigma=1, truncate=3 -> 7 taps), SAME zero padding.
// (N=2, D=160, H=160, W=160, C=4) float32 == float4 over C.
// Structure (round 5): no raw-LDS staging. Per slice:
//   - 88 "wblur workers" (22 rows x 4 col-groups) load a 10-float4 row span
//     straight from global (L1/L2 serves the halo overlap) and write 4
//     W-blurred float4s into a double-buffered wb LDS tile.
//   - single lgkmcnt-only barrier (no vmcnt drain; wb dbuf removes the 2nd
//     barrier a shared buffer would need).
//   - all 256 threads H-blur from wb (conflict-free column pattern) into a
//     7-deep register ring; D-blur of the ring -> coalesced store.
// LDS ops/slice: ~34 wave-b128 (was ~80); barriers/slice: 1 (was 2);
// LDS: 12KB (was 22.5KB).

#define TILE 16
#define CHUNK 16           // output D-slices per block -> 2000 blocks
#define DIM 160
#define SLICE (DIM * DIM)  // float4 elements per (D) slice

#define W0 0.004433048f
#define W1 0.054005582f
#define W2 0.242036229f
#define W3 0.399050300f

__device__ __forceinline__ float4 blur7(float4 a0, float4 a1, float4 a2, float4 a3,
                                        float4 a4, float4 a5, float4 a6) {
    float4 r;
    r.x = W0 * (a0.x + a6.x) + W1 * (a1.x + a5.x) + W2 * (a2.x + a4.x) + W3 * a3.x;
    r.y = W0 * (a0.y + a6.y) + W1 * (a1.y + a5.y) + W2 * (a2.y + a4.y) + W3 * a3.y;
    r.z = W0 * (a0.z + a6.z) + W1 * (a1.z + a5.z) + W2 * (a2.z + a4.z) + W3 * a3.z;
    r.w = W0 * (a0.w + a6.w) + W1 * (a1.w + a5.w) + W2 * (a2.w + a4.w) + W3 * a3.w;
    return r;
}

// Workgroup barrier with LDS visibility but NO vmcnt(0) drain.
__device__ __forceinline__ void lds_barrier() {
    asm volatile("s_waitcnt lgkmcnt(0)" ::: "memory");
    __builtin_amdgcn_s_barrier();
}

__global__ __launch_bounds__(256, 6)
void gauss3d_fused(const float4* __restrict__ in, float4* __restrict__ out) {
    // decode block: (tw, th, chunk, n)
    int bid = blockIdx.x;
    const int tw    = bid % (DIM / TILE);  bid /= (DIM / TILE);
    const int th    = bid % (DIM / TILE);  bid /= (DIM / TILE);
    const int chunk = bid % (DIM / CHUNK); bid /= (DIM / CHUNK);
    const int n     = bid;

    const int h0 = th * TILE;
    const int w0 = tw * TILE;
    const int d0 = chunk * CHUNK;

    // W-blurred tile, double-buffered: rows h0-3..h0+18 (22), cols w0..w0+15.
    __shared__ float4 wb[2][22][17];   // +1 col pad

    const int tid = threadIdx.x;
    const int lh = tid >> 4;       // 0..15
    const int lw = tid & 15;       // 0..15

    const size_t nbase = (size_t)n * DIM * SLICE;
    const float4 z = make_float4(0.f, 0.f, 0.f, 0.f);

    // ---- wblur worker constants (threads 0..87: 22 rows x 4 col-groups) ----
    const bool isW = (tid < 88);
    const int wr  = tid >> 2;         // 0..21  (row in wb)
    const int wc0 = (tid & 3) * 4;    // 0,4,8,12 (first of 4 output cols)
    const int grow = h0 + wr - 3;     // global row
    const bool row_ok = isW && (grow >= 0) && (grow < DIM);
    const int rowoff = row_ok ? grow * DIM : 0;
    // 10 input cols: w0 + wc0 - 3 + j, j=0..9 (clamped + validity bitmask)
    unsigned colmask = 0u;
    int gcol[10];
    #pragma unroll
    for (int j = 0; j < 10; ++j) {
        int gc = w0 + wc0 - 3 + j;
        bool ok = (gc >= 0) && (gc < DIM);
        gcol[j] = ok ? gc : 0;
        colmask |= (ok ? 1u : 0u) << j;
    }

    float4 r0 = z, r1 = z, r2 = z, r3 = z, r4 = z, r5 = z, r6 = z;
    int buf = 0;

    for (int din = d0 - 3; din <= d0 + CHUNK + 2; ++din) {
        const bool din_ok = (din >= 0) && (din < DIM);

        if (isW) {
            const float4* src =
                in + nbase + (size_t)(din_ok ? din : 0) * SLICE + rowoff;
            const bool base_ok = din_ok && row_ok;
            float4 rv[10];
            #pragma unroll
            for (int j = 0; j < 10; ++j)
                rv[j] = (base_ok && ((colmask >> j) & 1u)) ? src[gcol[j]] : z;
            #pragma unroll
            for (int m = 0; m < 4; ++m)
                wb[buf][wr][wc0 + m] = blur7(rv[m], rv[m + 1], rv[m + 2],
                                             rv[m + 3], rv[m + 4], rv[m + 5],
                                             rv[m + 6]);
        }

        lds_barrier();   // wb[buf] visible; prior reads of wb[buf] (2 iters
                         // ago) completed before the previous barrier.

        // H-blur at (lh, lw) -> register ring
        float4 v = blur7(wb[buf][lh][lw],     wb[buf][lh + 1][lw],
                         wb[buf][lh + 2][lw], wb[buf][lh + 3][lw],
                         wb[buf][lh + 4][lw], wb[buf][lh + 5][lw],
                         wb[buf][lh + 6][lw]);
        r0 = r1; r1 = r2; r2 = r3; r3 = r4; r4 = r5; r5 = r6; r6 = v;

        const int dout = din - 3;
        if (dout >= d0) {   // dout < d0+CHUNK guaranteed by loop bound
            float4 o = blur7(r0, r1, r2, r3, r4, r5, r6);
            out[nbase + ((size_t)dout * DIM + (h0 + lh)) * DIM + (w0 + lw)] = o;
        }
        buf ^= 1;
    }
}

extern "C" void kernel_launch(void* const* d_in, const int* in_sizes, int n_in,
                              void* d_out, int out_size, void* d_ws, size_t ws_size,
                              hipStream_t stream) {
    const float4* in = (const float4*)d_in[0];
    float4* out = (float4*)d_out;
    const int nblocks = 2 * (DIM / TILE) * (DIM / TILE) * (DIM / CHUNK); // 2000
    gauss3d_fused<<<nblocks, 256, 0, stream>>>(in, out);
}

// Round 6
// 80.499 us; speedup vs baseline: 2.6433x; 2.6433x over previous
//
#include <hip/hip_runtime.h>

// Separable 3D Gaussian blur (sigma=1, truncate=3 -> 7 taps), SAME zero padding.
// (N=2, D=160, H=160, W=160, C=4) float32 == float4 over C.
// Round 6: round-4 staged structure (coalesced global->LDS raw, prefetch one
// slice ahead, lgkmcnt-only barriers) with grouped blur phases to cut LDS ops:
//  - tile 16(H) x 32(W), CHUNK=16 D-slices -> 1000 blocks
//  - W-blur: 176 workers each read 10-f4 span from raw -> 4 wb outputs
//  - H-blur: each thread owns an H-PAIR: 8 wb reads -> 2 outputs, two 7-deep
//    D register rings
//  - odd f4-column pads (raw[39], wb[33]) -> ~2-way banks at 32B granule
// LDS wave-b128/slice ~83 for 512 outputs (round4: 80 for 256).

#define THT 16             // tile height (H outputs)
#define TWT 32             // tile width  (W outputs)
#define CHUNK 16           // output D-slices per block
#define DIM 160
#define SLICE (DIM * DIM)  // float4 elements per (D) slice
#define RAWN (22 * 38)     // staged halo elements per slice (838? 22*38=836)

#define W0 0.004433048f
#define W1 0.054005582f
#define W2 0.242036229f
#define W3 0.399050300f

__device__ __forceinline__ float4 blur7(float4 a0, float4 a1, float4 a2, float4 a3,
                                        float4 a4, float4 a5, float4 a6) {
    float4 r;
    r.x = W0 * (a0.x + a6.x) + W1 * (a1.x + a5.x) + W2 * (a2.x + a4.x) + W3 * a3.x;
    r.y = W0 * (a0.y + a6.y) + W1 * (a1.y + a5.y) + W2 * (a2.y + a4.y) + W3 * a3.y;
    r.z = W0 * (a0.z + a6.z) + W1 * (a1.z + a5.z) + W2 * (a2.z + a4.z) + W3 * a3.z;
    r.w = W0 * (a0.w + a6.w) + W1 * (a1.w + a5.w) + W2 * (a2.w + a4.w) + W3 * a3.w;
    return r;
}

// Workgroup barrier with LDS visibility but NO vmcnt(0) drain -> prefetched
// global loads stay in flight across it.
__device__ __forceinline__ void lds_barrier() {
    asm volatile("s_waitcnt lgkmcnt(0)" ::: "memory");
    __builtin_amdgcn_s_barrier();
}

__global__ __launch_bounds__(256, 4)
void gauss3d_fused(const float4* __restrict__ in, float4* __restrict__ out) {
    // decode block: (tw, th, chunk, n); W tiles: 5, H tiles: 10, chunks: 10
    int bid = blockIdx.x;
    const int tw    = bid % (DIM / TWT);   bid /= (DIM / TWT);
    const int th    = bid % (DIM / THT);   bid /= (DIM / THT);
    const int chunk = bid % (DIM / CHUNK); bid /= (DIM / CHUNK);
    const int n     = bid;

    const int h0 = th * THT;
    const int w0 = tw * TWT;
    const int d0 = chunk * CHUNK;

    __shared__ float4 raw[2][22][39];  // halo 22(H) x 38(W), odd pad, dbuf
    __shared__ float4 wb[22][33];      // W-blurred 22 x 32, odd pad

    const int tid = threadIdx.x;
    const size_t nbase = (size_t)n * DIM * SLICE;
    const float4 z = make_float4(0.f, 0.f, 0.f, 0.f);

    // ---- stage constants: 836 halo f4 over 256 threads (<=4 slots) ----
    int   soff[4];
    bool  sok[4];
    int   srow[4], scol[4];
    #pragma unroll
    for (int s = 0; s < 4; ++s) {
        const int i = tid + 256 * s;
        const bool has = (i < 22 * 38);
        const int rr = i / 38, cc = i % 38;
        const int gh = h0 + rr - 3, gw = w0 + cc - 3;
        const bool ok = has && gh >= 0 && gh < DIM && gw >= 0 && gw < DIM;
        soff[s] = ok ? (gh * DIM + gw) : 0;
        sok[s]  = ok;
        srow[s] = rr; scol[s] = cc;
        (void)srow; (void)scol;
    }

    // ---- W-blur worker constants: 176 workers = 22 rows x 8 groups of 4 ----
    const bool isW = (tid < 176);
    const int wr  = tid >> 3;        // 0..21
    const int wc0 = (tid & 7) * 4;   // 0,4,...,28

    // ---- H-blur constants: 256 threads = 8 H-pairs x 32 cols ----
    const int hp = tid >> 5;         // 0..7 -> output rows 2hp, 2hp+1
    const int lw = tid & 31;         // 0..31

    float4 pf0, pf1, pf2, pf3;
    float4 a0 = z, a1 = z, a2 = z, a3 = z, a4 = z, a5 = z, a6 = z;  // ring row 2hp
    float4 b0 = z, b1 = z, b2 = z, b3 = z, b4 = z, b5 = z, b6 = z;  // ring row 2hp+1

#define PREFETCH(DSL)                                                        \
    do {                                                                     \
        const int _d = (DSL);                                                \
        const bool _inr = (_d >= 0) && (_d < DIM);                           \
        const float4* _s = in + nbase + (size_t)(_inr ? _d : 0) * SLICE;     \
        pf0 = (_inr && sok[0]) ? _s[soff[0]] : z;                            \
        pf1 = (_inr && sok[1]) ? _s[soff[1]] : z;                            \
        pf2 = (_inr && sok[2]) ? _s[soff[2]] : z;                            \
        pf3 = (_inr && sok[3]) ? _s[soff[3]] : z;                            \
    } while (0)

    PREFETCH(d0 - 3);
    int buf = 0;

    for (int din = d0 - 3; din <= d0 + CHUNK + 2; ++din) {
        // 1) commit prefetched slice into raw[buf] (flat index = tid + 256s)
        {
            float4* rb = &raw[buf][0][0];
            // rows are padded to 39; flat store must respect pad: use rr,cc
            const int i0 = tid;
            rb[(i0 / 38) * 39 + (i0 % 38)] = pf0;
            const int i1 = tid + 256;
            rb[(i1 / 38) * 39 + (i1 % 38)] = pf1;
            const int i2 = tid + 512;
            rb[(i2 / 38) * 39 + (i2 % 38)] = pf2;
            if (tid + 768 < 22 * 38) {
                const int i3 = tid + 768;
                rb[(i3 / 38) * 39 + (i3 % 38)] = pf3;
            }
        }

        // 2) issue next slice's loads; in flight across both barriers
        PREFETCH(din + 1);

        lds_barrier();  // A: raw[buf] visible; prev hblur reads of wb drained

        // 3) W-blur: 176 workers, 10 raw reads -> 4 wb outputs each
        if (isW) {
            float4 rv0 = raw[buf][wr][wc0 + 0];
            float4 rv1 = raw[buf][wr][wc0 + 1];
            float4 rv2 = raw[buf][wr][wc0 + 2];
            float4 rv3 = raw[buf][wr][wc0 + 3];
            float4 rv4 = raw[buf][wr][wc0 + 4];
            float4 rv5 = raw[buf][wr][wc0 + 5];
            float4 rv6 = raw[buf][wr][wc0 + 6];
            float4 rv7 = raw[buf][wr][wc0 + 7];
            float4 rv8 = raw[buf][wr][wc0 + 8];
            float4 rv9 = raw[buf][wr][wc0 + 9];
            wb[wr][wc0 + 0] = blur7(rv0, rv1, rv2, rv3, rv4, rv5, rv6);
            wb[wr][wc0 + 1] = blur7(rv1, rv2, rv3, rv4, rv5, rv6, rv7);
            wb[wr][wc0 + 2] = blur7(rv2, rv3, rv4, rv5, rv6, rv7, rv8);
            wb[wr][wc0 + 3] = blur7(rv3, rv4, rv5, rv6, rv7, rv8, rv9);
        }

        lds_barrier();  // B: wb visible; raw[buf] reads drained (reuse at +2)

        // 4) H-blur pair: 8 wb reads -> 2 new ring values
        {
            float4 c0 = wb[2 * hp + 0][lw];
            float4 c1 = wb[2 * hp + 1][lw];
            float4 c2 = wb[2 * hp + 2][lw];
            float4 c3 = wb[2 * hp + 3][lw];
            float4 c4 = wb[2 * hp + 4][lw];
            float4 c5 = wb[2 * hp + 5][lw];
            float4 c6 = wb[2 * hp + 6][lw];
            float4 c7 = wb[2 * hp + 7][lw];
            float4 va = blur7(c0, c1, c2, c3, c4, c5, c6);
            float4 vb = blur7(c1, c2, c3, c4, c5, c6, c7);
            a0 = a1; a1 = a2; a2 = a3; a3 = a4; a4 = a5; a5 = a6; a6 = va;
            b0 = b1; b1 = b2; b2 = b3; b3 = b4; b4 = b5; b5 = b6; b6 = vb;
        }

        const int dout = din - 3;
        if (dout >= d0) {   // dout < d0+CHUNK by loop bound
            float4 oa = blur7(a0, a1, a2, a3, a4, a5, a6);
            float4 ob = blur7(b0, b1, b2, b3, b4, b5, b6);
            const size_t base = nbase + (size_t)dout * SLICE;
            out[base + (size_t)(h0 + 2 * hp + 0) * DIM + (w0 + lw)] = oa;
            out[base + (size_t)(h0 + 2 * hp + 1) * DIM + (w0 + lw)] = ob;
        }
        buf ^= 1;
    }
#undef PREFETCH
}

extern "C" void kernel_launch(void* const* d_in, const int* in_sizes, int n_in,
                              void* d_out, int out_size, void* d_ws, size_t ws_size,
                              hipStream_t stream) {
    const float4* in = (const float4*)d_in[0];
    float4* out = (float4*)d_out;
    const int nblocks =
        2 * (DIM / THT) * (DIM / TWT) * (DIM / CHUNK);  // 2*10*5*10 = 1000
    gauss3d_fused<<<nblocks, 256, 0, stream>>>(in, out);
}